// Round 2
// baseline (578.548 us; speedup 1.0000x reference)
//
#include <hip/hip_runtime.h>

// ImageWiseConv2d: per-sample conv, images [64,64,128,128] f32, kernels [64,64,3,3] f32
// out [64,1,126,126] f32 (VALID, stride 1).
//
// R1: split-K over channels for TLP. 2048 blocks = 64 samples x 8 row-tiles x 4
// channel-groups (16 ch each). Partials to d_ws [4][64][126][128] f32 (padded row
// stride 128 -> unguarded float4 stores), then a reduce kernel sums the 4 groups.
// Rationale: R0's 512-block version ran at 12% HBM BW — per-channel __syncthreads
// drains vmcnt(0) and with only 2 phase-locked blocks/CU nothing covers the drain.
// 8 blocks/CU of out-of-phase waves hide it. Epilogue pointer-select removed (SROA risk).

#define NS   64
#define CCH  64
#define HH   128
#define WW   128
#define OHH  126
#define OWW  126
#define TH   16      // output rows per tile
#define IR   18      // input rows per tile
#define LDW  132     // LDS row stride (floats)
#define LDW4 33      // LDS row stride in float4
#define NG   4       // channel groups (split-K)
#define CPG  16      // channels per group
#define PSTR 128     // padded partial row stride (floats)

__global__ __launch_bounds__(256, 4)
void ImageWiseConv2d_main(const float* __restrict__ img,
                          const float* __restrict__ ker,
                          float* __restrict__ part)
{
    __shared__ float buf[2][IR * LDW];

    const int tid = threadIdx.x;
    const int bx  = blockIdx.x;          // 0..2047
    const int bt  = bx & 7;              // row-tile
    const int n   = (bx >> 3) & 63;      // sample
    const int g   = bx >> 9;             // channel group 0..3
    const int h0  = bt * TH;

    // ---- loader mapping (float4 granularity; 18 rows x 32 float4) ----
    const int tx32 = tid & 31;           // float4 column 0..31
    const int rb   = tid >> 5;           // base row 0..7; +8, +16 chunks
    const float4* img4 = (const float4*)img;
    const int chstride4 = HH * WW / 4;   // 4096 float4 per channel
    int gbase = (n * CCH + g * CPG) * chstride4 + (h0 + rb) * (WW / 4) + tx32;
    const bool w2 = (rb < 2);                       // row rb+16 < 18
    const bool g2 = w2 && (h0 + rb + 16 < HH);      // and in-image
    const int lw0 = rb * LDW4 + tx32;

    // ---- compute mapping: thread = 2 rows x 4 cols of output ----
    const int tx = tid & 31;
    const int ty = tid >> 5;
    const int r0 = 2 * ty;
    const int c0 = 4 * tx;

    float acc0[4] = {0.f, 0.f, 0.f, 0.f};
    float acc1[4] = {0.f, 0.f, 0.f, 0.f};

    // ---- stage channel 0 of this group ----
    {
        float4 p0 = img4[gbase];
        float4 p1 = img4[gbase + 8 * (WW / 4)];
        float4 p2 = g2 ? img4[gbase + 16 * (WW / 4)] : make_float4(0.f, 0.f, 0.f, 0.f);
        float4* b0 = (float4*)buf[0];
        b0[lw0] = p0;
        b0[lw0 + 8 * LDW4] = p1;
        if (w2) b0[lw0 + 16 * LDW4] = p2;
    }
    __syncthreads();

    const float* __restrict__ kb = ker + (n * CCH + g * CPG) * 9;  // block-uniform

    for (int c = 0; c < CPG; ++c) {
        // prefetch next channel into registers
        float4 p0, p1, p2;
        const bool more = (c + 1 < CPG);
        if (more) {
            int gb = gbase + (c + 1) * chstride4;
            p0 = img4[gb];
            p1 = img4[gb + 8 * (WW / 4)];
            p2 = g2 ? img4[gb + 16 * (WW / 4)] : make_float4(0.f, 0.f, 0.f, 0.f);
        }

        float w[9];
        #pragma unroll
        for (int q = 0; q < 9; ++q) w[q] = kb[c * 9 + q];

        const float* bc = buf[c & 1];
        float f[4][8];
        #pragma unroll
        for (int r = 0; r < 4; ++r) {
            float4 a  = *(const float4*)&bc[(r0 + r) * LDW + c0];
            float4 b2 = *(const float4*)&bc[(r0 + r) * LDW + c0 + 4];
            f[r][0] = a.x;  f[r][1] = a.y;  f[r][2] = a.z;  f[r][3] = a.w;
            f[r][4] = b2.x; f[r][5] = b2.y; f[r][6] = b2.z; f[r][7] = b2.w;
        }

        #pragma unroll
        for (int kh = 0; kh < 3; ++kh) {
            #pragma unroll
            for (int kw = 0; kw < 3; ++kw) {
                const float wv = w[kh * 3 + kw];
                #pragma unroll
                for (int j = 0; j < 4; ++j) {
                    acc0[j] = fmaf(wv, f[kh][j + kw], acc0[j]);
                    acc1[j] = fmaf(wv, f[kh + 1][j + kw], acc1[j]);
                }
            }
        }

        if (more) {
            float4* bn = (float4*)buf[(c + 1) & 1];
            bn[lw0] = p0;
            bn[lw0 + 8 * LDW4] = p1;
            if (w2) bn[lw0 + 16 * LDW4] = p2;
            __syncthreads();
        }
    }

    // ---- store 2x4 partials, padded stride -> unguarded float4 (no pointer select) ----
    const int oh0 = h0 + r0;
    {
        const int oh = oh0;
        if (oh < OHH) {
            float* pp = part + ((g * NS + n) * OHH + oh) * PSTR + c0;
            *(float4*)pp = make_float4(acc0[0], acc0[1], acc0[2], acc0[3]);
        }
    }
    {
        const int oh = oh0 + 1;
        if (oh < OHH) {
            float* pp = part + ((g * NS + n) * OHH + oh) * PSTR + c0;
            *(float4*)pp = make_float4(acc1[0], acc1[1], acc1[2], acc1[3]);
        }
    }
}

__global__ __launch_bounds__(256)
void ImageWiseConv2d_reduce(const float* __restrict__ part,
                            float* __restrict__ out)
{
    const int i = blockIdx.x * 256 + threadIdx.x;
    const int total = NS * OHH * OWW;          // 1,016,064
    if (i >= total) return;
    const int n  = i / (OHH * OWW);
    const int r  = i - n * (OHH * OWW);
    const int oh = r / OWW;
    const int ow = r - oh * OWW;
    const int gs = NS * OHH * PSTR;            // per-group stride
    const int pb = (n * OHH + oh) * PSTR + ow;
    out[i] = part[pb] + part[pb + gs] + part[pb + 2 * gs] + part[pb + 3 * gs];
}

extern "C" void kernel_launch(void* const* d_in, const int* in_sizes, int n_in,
                              void* d_out, int out_size, void* d_ws, size_t ws_size,
                              hipStream_t stream) {
    const float* img = (const float*)d_in[0];   // [64,64,128,128] f32
    const float* ker = (const float*)d_in[1];   // [64,64,3,3] f32
    float* out  = (float*)d_out;                // [64,1,126,126] f32
    float* part = (float*)d_ws;                 // [4][64][126][128] f32 = 16.5 MB

    ImageWiseConv2d_main<<<dim3(NG * NS * 8), dim3(256), 0, stream>>>(img, ker, part);

    const int total = NS * OHH * OWW;
    ImageWiseConv2d_reduce<<<dim3((total + 255) / 256), dim3(256), 0, stream>>>(part, out);
}